// Round 1
// baseline (1745.101 us; speedup 1.0000x reference)
//
#include <hip/hip_runtime.h>
#include <hip/hip_bf16.h>
#include <type_traits>

// Problem constants (B=2, C=512, H=W=64 -> N=4096, 32 groups)
#define BATCH 2
#define CDIM 512
#define NDIM 4096
#define NGROUPS 32
#define CH_PER_G (CDIM / NGROUPS)
#define GN_EPS 1e-6f

static __device__ __forceinline__ float to_f32(float v) { return v; }
static __device__ __forceinline__ float to_f32(__hip_bfloat16 v) { return __bfloat162float(v); }

template <typename T>
static __device__ __forceinline__ T from_f32(float v) {
  if constexpr (std::is_same<T, __hip_bfloat16>::value) return __float2bfloat16(v);
  else return v;
}

// ---------------- GroupNorm ----------------
// one block per (batch, group); group data is contiguous: CH_PER_G * NDIM floats
__global__ __launch_bounds__(256) void groupnorm_kernel(
    const float* __restrict__ x, const float* __restrict__ w,
    const float* __restrict__ bias, float* __restrict__ out) {
  int bg = blockIdx.x;
  int g = bg % NGROUPS, b = bg / NGROUPS;
  size_t base = ((size_t)b * CDIM + (size_t)g * CH_PER_G) * NDIM;
  const int len = CH_PER_G * NDIM;  // 65536
  float s = 0.f, ss = 0.f;
  for (int i = threadIdx.x; i < len; i += 256) {
    float v = x[base + i];
    s += v; ss += v * v;
  }
  __shared__ float r1[256], r2[256];
  r1[threadIdx.x] = s; r2[threadIdx.x] = ss;
  __syncthreads();
  for (int off = 128; off > 0; off >>= 1) {
    if (threadIdx.x < off) { r1[threadIdx.x] += r1[threadIdx.x + off]; r2[threadIdx.x] += r2[threadIdx.x + off]; }
    __syncthreads();
  }
  float mean = r1[0] / len;
  float var = r2[0] / len - mean * mean;
  float rs = rsqrtf(var + GN_EPS);
  for (int i = threadIdx.x; i < len; i += 256) {
    int c = g * CH_PER_G + (i >> 12);  // i / NDIM
    float v = (x[base + i] - mean) * rs;
    out[base + i] = v * w[c] + bias[c];
  }
}

// ---------------- Generic tiled GEMM ----------------
// C[m,n] = scale * sum_k A[m,k] * B[k,n]  (+ bias[m]) (+ res[m,n])
// A row-major M x K (fp32), B row-major K x N (TB), out row-major (or transposed).
// Tiles: 64x64, BK=16, 256 threads, 4x4 per thread. M,N,K all divisible.
template <typename TB, typename TOut, bool TRANS_OUT, bool HAS_BIAS, bool HAS_RES>
__global__ __launch_bounds__(256) void gemm_kernel(
    const float* __restrict__ A, const TB* __restrict__ B,
    const float* __restrict__ bias, const float* __restrict__ res,
    TOut* __restrict__ Cout,
    int M, int N, int K, long sA, long sB, long sC, long sRes, float scale) {
  __shared__ float As[16][64];
  __shared__ float Bs[16][64];
  int b = blockIdx.z;
  A += (size_t)b * sA;
  B += (size_t)b * sB;
  Cout += (size_t)b * sC;
  const float* resb = nullptr;
  if (HAS_RES) resb = res + (size_t)b * sRes;
  int m0 = blockIdx.y * 64, n0 = blockIdx.x * 64;
  int tid = threadIdx.x;
  int ty = tid >> 4, tx = tid & 15;
  float acc[4][4] = {};
  for (int k0 = 0; k0 < K; k0 += 16) {
#pragma unroll
    for (int t = 0; t < 4; t++) {
      int idx = tid + t * 256;           // 0..1023
      int mm = idx >> 4, kk = idx & 15;  // A tile 64x16
      As[kk][mm] = A[(size_t)(m0 + mm) * K + k0 + kk];
    }
#pragma unroll
    for (int t = 0; t < 4; t++) {
      int idx = tid + t * 256;
      int kk = idx >> 6, nn = idx & 63;  // B tile 16x64
      Bs[kk][nn] = to_f32(B[(size_t)(k0 + kk) * N + n0 + nn]);
    }
    __syncthreads();
#pragma unroll
    for (int kk = 0; kk < 16; kk++) {
      float a[4], bb[4];
#pragma unroll
      for (int r = 0; r < 4; r++) a[r] = As[kk][ty * 4 + r];
#pragma unroll
      for (int s = 0; s < 4; s++) bb[s] = Bs[kk][tx * 4 + s];
#pragma unroll
      for (int r = 0; r < 4; r++)
#pragma unroll
        for (int s = 0; s < 4; s++) acc[r][s] += a[r] * bb[s];
    }
    __syncthreads();
  }
#pragma unroll
  for (int r = 0; r < 4; r++) {
    int m = m0 + ty * 4 + r;
    float bv = HAS_BIAS ? bias[m] : 0.f;
#pragma unroll
    for (int s = 0; s < 4; s++) {
      int n = n0 + tx * 4 + s;
      float v = acc[r][s] * scale + bv;
      if (HAS_RES) v += resb[(size_t)m * N + n];
      if (TRANS_OUT) Cout[(size_t)n * M + m] = from_f32<TOut>(v);
      else Cout[(size_t)m * N + n] = from_f32<TOut>(v);
    }
  }
}

// ---------------- Row softmax (in place, bf16, row length = NDIM = 4096) ----------------
__global__ __launch_bounds__(256) void softmax_kernel(__hip_bfloat16* __restrict__ S) {
  size_t row = blockIdx.x;
  __hip_bfloat16* p = S + row * NDIM;
  int tid = threadIdx.x;
  float v[16];
  float m = -1e30f;
#pragma unroll
  for (int t = 0; t < 16; t++) {
    v[t] = __bfloat162float(p[tid + t * 256]);
    m = fmaxf(m, v[t]);
  }
  __shared__ float red[256];
  red[tid] = m;
  __syncthreads();
  for (int off = 128; off > 0; off >>= 1) {
    if (tid < off) red[tid] = fmaxf(red[tid], red[tid + off]);
    __syncthreads();
  }
  m = red[0];
  __syncthreads();
  float s = 0.f;
#pragma unroll
  for (int t = 0; t < 16; t++) {
    v[t] = __expf(v[t] - m);
    s += v[t];
  }
  red[tid] = s;
  __syncthreads();
  for (int off = 128; off > 0; off >>= 1) {
    if (tid < off) red[tid] += red[tid + off];
    __syncthreads();
  }
  float inv = 1.0f / red[0];
#pragma unroll
  for (int t = 0; t < 16; t++) p[tid + t * 256] = __float2bfloat16(v[t] * inv);
}

extern "C" void kernel_launch(void* const* d_in, const int* in_sizes, int n_in,
                              void* d_out, int out_size, void* d_ws, size_t ws_size,
                              hipStream_t stream) {
  const float* x      = (const float*)d_in[0];
  const float* norm_w = (const float*)d_in[1];
  const float* norm_b = (const float*)d_in[2];
  const float* wq = (const float*)d_in[3];
  const float* bq = (const float*)d_in[4];
  const float* wk = (const float*)d_in[5];
  const float* bk = (const float*)d_in[6];
  const float* wv = (const float*)d_in[7];
  const float* bv = (const float*)d_in[8];
  const float* wp = (const float*)d_in[9];
  const float* bp = (const float*)d_in[10];
  float* out = (float*)d_out;

  const long CN = (long)CDIM * NDIM;    // 2M elems
  const long NN = (long)NDIM * NDIM;    // 16M elems
  char* p = (char*)d_ws;
  float* h_norm = (float*)p;            p += sizeof(float) * BATCH * CN;
  float* qt     = (float*)p;            p += sizeof(float) * BATCH * CN;  // [B, N, C]
  float* kbuf   = (float*)p;            p += sizeof(float) * BATCH * CN;  // [B, C, N]
  float* vbuf   = (float*)p;            p += sizeof(float) * BATCH * CN;  // [B, C, N]
  float* hattn  = (float*)p;            p += sizeof(float) * BATCH * CN;  // [B, C, N]
  __hip_bfloat16* S = (__hip_bfloat16*)p;  // [B, N, N] scores -> probs in place

  const float scale = 0.044194173824159216f;  // 512^-0.5

  // 1. GroupNorm
  groupnorm_kernel<<<dim3(BATCH * NGROUPS), dim3(256), 0, stream>>>(x, norm_w, norm_b, h_norm);

  // 2. q (transposed out), k, v projections
  gemm_kernel<float, float, true, true, false><<<dim3(NDIM / 64, CDIM / 64, BATCH), 256, 0, stream>>>(
      wq, h_norm, bq, nullptr, qt, CDIM, NDIM, CDIM, 0, CN, CN, 0, 1.0f);
  gemm_kernel<float, float, false, true, false><<<dim3(NDIM / 64, CDIM / 64, BATCH), 256, 0, stream>>>(
      wk, h_norm, bk, nullptr, kbuf, CDIM, NDIM, CDIM, 0, CN, CN, 0, 1.0f);
  gemm_kernel<float, float, false, true, false><<<dim3(NDIM / 64, CDIM / 64, BATCH), 256, 0, stream>>>(
      wv, h_norm, bv, nullptr, vbuf, CDIM, NDIM, CDIM, 0, CN, CN, 0, 1.0f);

  // 3. S = scale * qt @ k   [B, N, N] bf16
  gemm_kernel<float, __hip_bfloat16, false, false, false><<<dim3(NDIM / 64, NDIM / 64, BATCH), 256, 0, stream>>>(
      qt, kbuf, nullptr, nullptr, S, NDIM, NDIM, CDIM, CN, CN, NN, 0, scale);

  // 4. row softmax in place
  softmax_kernel<<<dim3(BATCH * NDIM), dim3(256), 0, stream>>>(S);

  // 5. h = v @ P   [B, C, N]
  gemm_kernel<__hip_bfloat16, float, false, false, false><<<dim3(NDIM / 64, CDIM / 64, BATCH), 256, 0, stream>>>(
      vbuf, S, nullptr, nullptr, hattn, CDIM, NDIM, NDIM, CN, NN, CN, 0, 1.0f);

  // 6. out = x + wp @ h + bp
  gemm_kernel<float, float, false, true, true><<<dim3(NDIM / 64, CDIM / 64, BATCH), 256, 0, stream>>>(
      wp, hattn, bp, x, out, CDIM, NDIM, CDIM, 0, CN, CN, CN, 1.0f);
}

// Round 2
// 451.854 us; speedup vs baseline: 3.8621x; 3.8621x over previous
//
#include <hip/hip_runtime.h>
#include <hip/hip_bf16.h>

// B=2, C=512, H=W=64 -> N=4096, 32 groups of 16 channels
#define BATCH 2
#define CDIM 512
#define NDIM 4096
#define NGROUPS 32
#define CHPG 16
#define GN_EPS 1e-6f

typedef __attribute__((ext_vector_type(8))) short bf16x8;   // 8 bf16 = 4 VGPRs
typedef __attribute__((ext_vector_type(4))) float f32x4;

__device__ __forceinline__ void gl_lds16(const void* g, void* lds) {
  __builtin_amdgcn_global_load_lds((__attribute__((address_space(1))) void*)(g),
                                   (__attribute__((address_space(3))) void*)(lds), 16, 0, 0);
}

// ---------------- GroupNorm stats: one block per (b, g) ----------------
__global__ __launch_bounds__(256) void gn_stats(const float* __restrict__ x,
                                                float2* __restrict__ stats) {
  int bg = blockIdx.x;  // b*32+g ; group channels are contiguous
  size_t base = (size_t)bg * CHPG * NDIM;
  const int len = CHPG * NDIM;  // 65536
  float s = 0.f, ss = 0.f;
  for (int i = threadIdx.x; i < len; i += 256) {
    float v = x[base + i];
    s += v; ss += v * v;
  }
  __shared__ float r1[256], r2[256];
  r1[threadIdx.x] = s; r2[threadIdx.x] = ss;
  __syncthreads();
  for (int off = 128; off > 0; off >>= 1) {
    if (threadIdx.x < off) { r1[threadIdx.x] += r1[threadIdx.x + off]; r2[threadIdx.x] += r2[threadIdx.x + off]; }
    __syncthreads();
  }
  if (threadIdx.x == 0) {
    float mean = r1[0] / len;
    float var = r2[0] / len - mean * mean;
    stats[bg] = make_float2(mean, rsqrtf(var + GN_EPS));
  }
}

// ------ GroupNorm apply + transpose to channel-last bf16: h_t[b][n][c] ------
__global__ __launch_bounds__(256) void gn_apply_t(const float* __restrict__ x,
                                                  const float2* __restrict__ stats,
                                                  const float* __restrict__ w,
                                                  const float* __restrict__ bias,
                                                  __hip_bfloat16* __restrict__ ht) {
  __shared__ __hip_bfloat16 tile[64][66];  // 66: bank-conflict pad
  int b = blockIdx.z, c0 = blockIdx.y * 64, n0 = blockIdx.x * 64;
  int tq = threadIdx.x >> 6;   // 0..3
  int tl = threadIdx.x & 63;
#pragma unroll
  for (int i = 0; i < 16; i++) {
    int cl = tq * 16 + i;
    int c = c0 + cl;
    float2 st = stats[b * NGROUPS + (c >> 4)];
    float v = x[((size_t)b * CDIM + c) * NDIM + n0 + tl];
    v = (v - st.x) * st.y * w[c] + bias[c];
    tile[tl][cl] = __float2bfloat16(v);
  }
  __syncthreads();
#pragma unroll
  for (int i = 0; i < 16; i++) {
    int nl = tq * 16 + i;
    ht[((size_t)b * NDIM + n0 + nl) * CDIM + c0 + tl] = tile[nl][tl];
  }
}

// ------------- fp32 -> bf16 for the four 512x512 weights -------------
__global__ __launch_bounds__(256) void cvt_w(const float* __restrict__ a, const float* __restrict__ b,
                                             const float* __restrict__ c, const float* __restrict__ d,
                                             __hip_bfloat16* __restrict__ o) {
  int i = blockIdx.x * 256 + threadIdx.x;  // 0..262143
  o[i]          = __float2bfloat16(a[i]);
  o[i + 262144] = __float2bfloat16(b[i]);
  o[i + 524288] = __float2bfloat16(c[i]);
  o[i + 786432] = __float2bfloat16(d[i]);
}

// ---------------- MFMA NT GEMM ----------------
// C[m][n] = scale * sum_k A[m][k]*B[n][k]  (+bias)  (+res)
// A: [M,K] bf16 row-major, B: [N,K] bf16 row-major. 128x128 tile, BK=32.
// BIAS_MODE: 0 none, 1 bias[m], 2 bias[n].
template <int BIAS_MODE, bool HAS_RES, bool OUT_F32>
__global__ __launch_bounds__(256, 2) void mfma_gemm_nt(
    const __hip_bfloat16* __restrict__ A, const __hip_bfloat16* __restrict__ B,
    const float* __restrict__ bias, const float* __restrict__ res,
    void* __restrict__ Cout, int M, int N, int K,
    long sA, long sB, long sC, float scale) {
  __shared__ __hip_bfloat16 As[128 * 32];  // 8 KB, row-major [128][32]
  __shared__ __hip_bfloat16 Bs[128 * 32];  // 8 KB, row-major [128][32] (rows = N-dim)
  const int tid = threadIdx.x;
  const int w = tid >> 6, l = tid & 63;
  const int wy = w >> 1, wx = w & 1;       // 2x2 wave grid, 64x64 per wave
  const int bz = blockIdx.z;
  const __hip_bfloat16* Ab = A + (size_t)bz * sA;
  const __hip_bfloat16* Bb = B + (size_t)bz * sB;
  const int m0 = blockIdx.y * 128, n0 = blockIdx.x * 128;
  f32x4 acc[4][4] = {};
  // staging: each wave issue covers 16 rows x 64B; lane l -> row (l>>2), byte (l&3)*16
  const int srow = w * 32 + (l >> 2);
  const char* Ag = (const char*)(Ab + (size_t)(m0 + srow) * K) + (l & 3) * 16;
  const char* Bg = (const char*)(Bb + (size_t)(n0 + srow) * K) + (l & 3) * 16;
  char* Al = (char*)As + w * 2048;
  char* Bl = (char*)Bs + w * 2048;
  const size_t radv = (size_t)K * 2 * 16;  // +16 rows
  for (int k0 = 0; k0 < K; k0 += 32) {
    gl_lds16(Ag, Al);
    gl_lds16(Ag + radv, Al + 1024);
    gl_lds16(Bg, Bl);
    gl_lds16(Bg + radv, Bl + 1024);
    Ag += 64; Bg += 64;
    __syncthreads();  // drains vmcnt before barrier
    bf16x8 af[4], bfr[4];
#pragma unroll
    for (int t = 0; t < 4; t++) {
      af[t]  = *(const bf16x8*)(As + (wy * 64 + t * 16 + (l & 15)) * 32 + (l >> 4) * 8);
      bfr[t] = *(const bf16x8*)(Bs + (wx * 64 + t * 16 + (l & 15)) * 32 + (l >> 4) * 8);
    }
#pragma unroll
    for (int mt = 0; mt < 4; mt++)
#pragma unroll
      for (int nt = 0; nt < 4; nt++)
        acc[mt][nt] = __builtin_amdgcn_mfma_f32_16x16x32_bf16(af[mt], bfr[nt], acc[mt][nt], 0, 0, 0);
    __syncthreads();
  }
  // epilogue: D row = (l>>4)*4 + r, col = l&15  [m89-verified mapping]
  const size_t cbase = (size_t)bz * sC;
#pragma unroll
  for (int mt = 0; mt < 4; mt++) {
#pragma unroll
    for (int r = 0; r < 4; r++) {
      const int m = m0 + wy * 64 + mt * 16 + (l >> 4) * 4 + r;
      float bv = (BIAS_MODE == 1) ? bias[m] : 0.f;
#pragma unroll
      for (int nt = 0; nt < 4; nt++) {
        const int n = n0 + wx * 64 + nt * 16 + (l & 15);
        float v = acc[mt][nt][r] * scale + bv;
        if (BIAS_MODE == 2) v += bias[n];
        if (HAS_RES) v += res[cbase + (size_t)m * N + n];
        if (OUT_F32) ((float*)Cout)[cbase + (size_t)m * N + n] = v;
        else ((__hip_bfloat16*)Cout)[cbase + (size_t)m * N + n] = __float2bfloat16(v);
      }
    }
  }
}

// ---------------- Column softmax over St[j][i] (normalize over rows j) ----------------
// p1: per-(colblock, rowchunk) online max/sum; p2: combine; p3: apply.
__global__ __launch_bounds__(256) void softmax_p1(const __hip_bfloat16* __restrict__ St,
                                                  float* __restrict__ pmax, float* __restrict__ psum) {
  int b = blockIdx.z;
  int i = blockIdx.x * 256 + threadIdx.x;
  int j0 = blockIdx.y * 512;
  const __hip_bfloat16* p = St + (size_t)b * NDIM * NDIM + (size_t)j0 * NDIM + i;
  float m = -1e30f, s = 0.f;
  for (int j = 0; j < 512; j++) {
    float v = __bfloat162float(p[(size_t)j * NDIM]);
    float mn = fmaxf(m, v);
    s = s * __expf(m - mn) + __expf(v - mn);
    m = mn;
  }
  int idx = (b * 8 + blockIdx.y) * NDIM + i;
  pmax[idx] = m; psum[idx] = s;
}

__global__ __launch_bounds__(256) void softmax_p2(const float* __restrict__ pmax,
                                                  const float* __restrict__ psum,
                                                  float* __restrict__ cmax, float* __restrict__ cinv) {
  int idx = blockIdx.x * 256 + threadIdx.x;  // b*NDIM + i, 8192 total
  int b = idx >> 12, i = idx & (NDIM - 1);
  float M = -1e30f;
#pragma unroll
  for (int rc = 0; rc < 8; rc++) M = fmaxf(M, pmax[(b * 8 + rc) * NDIM + i]);
  float s = 0.f;
#pragma unroll
  for (int rc = 0; rc < 8; rc++) s += psum[(b * 8 + rc) * NDIM + i] * __expf(pmax[(b * 8 + rc) * NDIM + i] - M);
  cmax[idx] = M; cinv[idx] = 1.0f / s;
}

__global__ __launch_bounds__(256) void softmax_p3(__hip_bfloat16* __restrict__ St,
                                                  const float* __restrict__ cmax,
                                                  const float* __restrict__ cinv) {
  int b = blockIdx.z;
  int i = blockIdx.x * 256 + threadIdx.x;
  int j0 = blockIdx.y * 512;
  float M = cmax[b * NDIM + i], inv = cinv[b * NDIM + i];
  __hip_bfloat16* p = St + (size_t)b * NDIM * NDIM + (size_t)j0 * NDIM + i;
  for (int j = 0; j < 512; j++) {
    float v = __bfloat162float(p[(size_t)j * NDIM]);
    p[(size_t)j * NDIM] = __float2bfloat16(__expf(v - M) * inv);
  }
}

extern "C" void kernel_launch(void* const* d_in, const int* in_sizes, int n_in,
                              void* d_out, int out_size, void* d_ws, size_t ws_size,
                              hipStream_t stream) {
  const float* x      = (const float*)d_in[0];
  const float* norm_w = (const float*)d_in[1];
  const float* norm_b = (const float*)d_in[2];
  const float* wq = (const float*)d_in[3];
  const float* bq = (const float*)d_in[4];
  const float* wk = (const float*)d_in[5];
  const float* bk = (const float*)d_in[6];
  const float* wv = (const float*)d_in[7];
  const float* bv = (const float*)d_in[8];
  const float* wp = (const float*)d_in[9];
  const float* bp = (const float*)d_in[10];
  float* out = (float*)d_out;

  const long CN = (long)CDIM * NDIM;   // 2M elems
  const long NN = (long)NDIM * NDIM;   // 16M elems
  char* p = (char*)d_ws;
  auto carve = [&](size_t bytes) { char* r = p; p += (bytes + 255) & ~(size_t)255; return r; };
  __hip_bfloat16* h_t  = (__hip_bfloat16*)carve(BATCH * CN * 2);  // [B,N,C]
  __hip_bfloat16* wb   = (__hip_bfloat16*)carve(4 * 512 * 512 * 2);
  __hip_bfloat16* q_t  = (__hip_bfloat16*)carve(BATCH * CN * 2);  // [B,N,C]
  __hip_bfloat16* k_t  = (__hip_bfloat16*)carve(BATCH * CN * 2);  // [B,N,C]
  __hip_bfloat16* vb   = (__hip_bfloat16*)carve(BATCH * CN * 2);  // [B,C,N]
  __hip_bfloat16* ht2  = (__hip_bfloat16*)carve(BATCH * CN * 2);  // [B,N,C]
  __hip_bfloat16* St   = (__hip_bfloat16*)carve(BATCH * NN * 2);  // [B,N,N] S^T -> P^T
  float2* stats = (float2*)carve(BATCH * NGROUPS * sizeof(float2));
  float* pmax = (float*)carve(BATCH * 8 * NDIM * 4);
  float* psum = (float*)carve(BATCH * 8 * NDIM * 4);
  float* cmax = (float*)carve(BATCH * NDIM * 4);
  float* cinv = (float*)carve(BATCH * NDIM * 4);
  __hip_bfloat16* wbq = wb;
  __hip_bfloat16* wbk = wb + 262144;
  __hip_bfloat16* wbv = wb + 524288;
  __hip_bfloat16* wbp = wb + 786432;

  const float scale = 0.044194173824159216f;  // 512^-0.5

  gn_stats<<<dim3(BATCH * NGROUPS), 256, 0, stream>>>(x, stats);
  gn_apply_t<<<dim3(NDIM / 64, CDIM / 64, BATCH), 256, 0, stream>>>(x, stats, norm_w, norm_b, h_t);
  cvt_w<<<dim3(1024), 256, 0, stream>>>(wq, wk, wv, wp, wb);

  // q_t[b] = h_t[b] @ wq^T + bq  -> [N, C]
  mfma_gemm_nt<2, false, false><<<dim3(CDIM / 128, NDIM / 128, BATCH), 256, 0, stream>>>(
      h_t, wbq, bq, nullptr, q_t, NDIM, CDIM, CDIM, CN, 0, CN, 1.0f);
  // k_t[b] = h_t[b] @ wk^T + bk  -> [N, C]
  mfma_gemm_nt<2, false, false><<<dim3(CDIM / 128, NDIM / 128, BATCH), 256, 0, stream>>>(
      h_t, wbk, bk, nullptr, k_t, NDIM, CDIM, CDIM, CN, 0, CN, 1.0f);
  // v[b] = wv @ h_t[b]^T + bv  -> [C, N]
  mfma_gemm_nt<1, false, false><<<dim3(NDIM / 128, CDIM / 128, BATCH), 256, 0, stream>>>(
      wbv, h_t, bv, nullptr, vb, CDIM, NDIM, CDIM, 0, CN, CN, 1.0f);
  // St[b] = k_t[b] @ q_t[b]^T * scale  -> [N, N]  (St[j][i] = S[i][j])
  mfma_gemm_nt<0, false, false><<<dim3(NDIM / 128, NDIM / 128, BATCH), 256, 0, stream>>>(
      k_t, q_t, nullptr, nullptr, St, NDIM, NDIM, CDIM, CN, CN, NN, scale);
  // softmax over j (rows of St), per column i
  softmax_p1<<<dim3(16, 8, BATCH), 256, 0, stream>>>(St, pmax, psum);
  softmax_p2<<<dim3(32), 256, 0, stream>>>(pmax, psum, cmax, cinv);
  softmax_p3<<<dim3(16, 8, BATCH), 256, 0, stream>>>(St, cmax, cinv);
  // ht2[b] = Pt[b] @ v[b]^T -> [N, C]
  mfma_gemm_nt<0, false, false><<<dim3(CDIM / 128, NDIM / 128, BATCH), 256, 0, stream>>>(
      St, vb, nullptr, nullptr, ht2, NDIM, CDIM, NDIM, NN, CN, CN, 1.0f);
  // out[b] = wp @ ht2[b]^T + bp + x  -> [C, N] fp32
  mfma_gemm_nt<1, true, true><<<dim3(NDIM / 128, CDIM / 128, BATCH), 256, 0, stream>>>(
      wbp, ht2, bp, x, out, CDIM, NDIM, CDIM, 0, CN, CN, 1.0f);
}

// Round 3
// 338.630 us; speedup vs baseline: 5.1534x; 1.3344x over previous
//
#include <hip/hip_runtime.h>
#include <hip/hip_bf16.h>

// B=2, C=512, H=W=64 -> N=4096, 32 groups of 16 channels
#define BATCH 2
#define CDIM 512
#define NDIM 4096
#define NGROUPS 32
#define CHPG 16
#define GN_EPS 1e-6f

typedef __attribute__((ext_vector_type(8))) short bf16x8;   // 8 bf16 = 4 VGPRs
typedef __attribute__((ext_vector_type(4))) float f32x4;

__device__ __forceinline__ void gl_lds16(const void* g, void* lds) {
  __builtin_amdgcn_global_load_lds((__attribute__((address_space(1))) void*)(g),
                                   (__attribute__((address_space(3))) void*)(lds), 16, 0, 0);
}

// ---------------- GroupNorm stats, two-stage ----------------
// p1: grid = 64 groups * 16 chunks; each block reduces 4096 floats (float4).
__global__ __launch_bounds__(256) void gn_stats_p1(const float* __restrict__ x,
                                                   float2* __restrict__ part) {
  int blk = blockIdx.x;
  int chunk = blk & 15, bg = blk >> 4;
  const float4* p = (const float4*)(x + (size_t)bg * (CHPG * NDIM) + chunk * 4096);
  float s = 0.f, ss = 0.f;
#pragma unroll
  for (int t = 0; t < 4; t++) {
    float4 v = p[threadIdx.x + t * 256];
    s += v.x + v.y + v.z + v.w;
    ss += v.x * v.x + v.y * v.y + v.z * v.z + v.w * v.w;
  }
  int w = threadIdx.x >> 6, l = threadIdx.x & 63;
#pragma unroll
  for (int off = 32; off > 0; off >>= 1) {
    s += __shfl_down(s, off);
    ss += __shfl_down(ss, off);
  }
  __shared__ float r1[4], r2[4];
  if (l == 0) { r1[w] = s; r2[w] = ss; }
  __syncthreads();
  if (threadIdx.x == 0)
    part[blk] = make_float2(r1[0] + r1[1] + r1[2] + r1[3], r2[0] + r2[1] + r2[2] + r2[3]);
}

__global__ __launch_bounds__(64) void gn_stats_p2(const float2* __restrict__ part,
                                                  float2* __restrict__ stats) {
  int bg = threadIdx.x;  // 64
  float s = 0.f, ss = 0.f;
#pragma unroll
  for (int c = 0; c < 16; c++) {
    float2 v = part[bg * 16 + c];
    s += v.x; ss += v.y;
  }
  const float inv = 1.0f / (CHPG * NDIM);
  float mean = s * inv;
  float var = ss * inv - mean * mean;
  stats[bg] = make_float2(mean, rsqrtf(var + GN_EPS));
}

// ------ GroupNorm apply + transpose to channel-last bf16: h_t[b][n][c] ------
__global__ __launch_bounds__(256) void gn_apply_t(const float* __restrict__ x,
                                                  const float2* __restrict__ stats,
                                                  const float* __restrict__ w,
                                                  const float* __restrict__ bias,
                                                  __hip_bfloat16* __restrict__ ht) {
  __shared__ __hip_bfloat16 tile[64][66];
  int b = blockIdx.z, c0 = blockIdx.y * 64, n0 = blockIdx.x * 64;
  int tq = threadIdx.x >> 6;
  int tl = threadIdx.x & 63;
#pragma unroll
  for (int i = 0; i < 16; i++) {
    int cl = tq * 16 + i;
    int c = c0 + cl;
    float2 st = stats[b * NGROUPS + (c >> 4)];
    float v = x[((size_t)b * CDIM + c) * NDIM + n0 + tl];
    v = (v - st.x) * st.y * w[c] + bias[c];
    tile[tl][cl] = __float2bfloat16(v);
  }
  __syncthreads();
#pragma unroll
  for (int i = 0; i < 16; i++) {
    int nl = tq * 16 + i;
    ht[((size_t)b * NDIM + n0 + nl) * CDIM + c0 + tl] = tile[nl][tl];
  }
}

// ------------- fp32 -> bf16 for the four 512x512 weights -------------
__global__ __launch_bounds__(256) void cvt_w(const float* __restrict__ a, const float* __restrict__ b,
                                             const float* __restrict__ c, const float* __restrict__ d,
                                             __hip_bfloat16* __restrict__ o) {
  int i = blockIdx.x * 256 + threadIdx.x;
  o[i]          = __float2bfloat16(a[i]);
  o[i + 262144] = __float2bfloat16(b[i]);
  o[i + 524288] = __float2bfloat16(c[i]);
  o[i + 786432] = __float2bfloat16(d[i]);
}

// ---------------- MFMA NT GEMM, MT x NT tile ----------------
// C[m][n] = scale * sum_k A[m][k]*B[n][k]  (+bias) (+res)
// A: [M,K] bf16, B: [N,K] bf16, both row-major. BK=32, 4 waves (2x2).
// BIAS_MODE: 0 none, 1 bias[m], 2 bias[n]. STATS (needs 128x128): write
// per-block column max & sum-of-exp to pmax/psum [gridDim.y][N] per batch.
template <int MT, int NT, int BIAS_MODE, bool HAS_RES, bool OUT_F32, bool STATS>
__global__ __launch_bounds__(256, 2) void mfma_gemm_nt(
    const __hip_bfloat16* __restrict__ A, const __hip_bfloat16* __restrict__ B,
    const float* __restrict__ bias, const float* __restrict__ res,
    void* __restrict__ Cout, float* __restrict__ pmax_g, float* __restrict__ psum_g,
    int M, int N, int K, long sA, long sB, long sC, float scale) {
  constexpr int MTI = MT / 32, NTI = NT / 32;   // 16x16 acc tiles per wave
  __shared__ __hip_bfloat16 As[MT * 32];
  __shared__ __hip_bfloat16 Bs[NT * 32];
  const int tid = threadIdx.x;
  const int w = tid >> 6, l = tid & 63;
  const int wy = w >> 1, wx = w & 1;
  const int bz = blockIdx.z;
  const int m0 = blockIdx.y * MT, n0 = blockIdx.x * NT;
  f32x4 acc[MTI][NTI] = {};
  // staging: one gl_lds16 issue = 64 lanes x 16B = 16 rows x 64B
  const int arow = w * (MT / 4) + (l >> 2);
  const int brow = w * (NT / 4) + (l >> 2);
  const char* Ag = (const char*)(A + (size_t)bz * sA + (size_t)(m0 + arow) * K) + (l & 3) * 16;
  const char* Bg = (const char*)(B + (size_t)bz * sB + (size_t)(n0 + brow) * K) + (l & 3) * 16;
  char* Al = (char*)As + w * (MT * 16);
  char* Bl = (char*)Bs + w * (NT * 16);
  const size_t radv = (size_t)K * 32;  // +16 rows (bf16)
  for (int k0 = 0; k0 < K; k0 += 32) {
    gl_lds16(Ag, Al);
    if (MT == 128) gl_lds16(Ag + radv, Al + 1024);
    gl_lds16(Bg, Bl);
    if (NT == 128) gl_lds16(Bg + radv, Bl + 1024);
    Ag += 64; Bg += 64;
    __syncthreads();
    bf16x8 af[MTI], bfr[NTI];
#pragma unroll
    for (int mt = 0; mt < MTI; mt++)
      af[mt] = *(const bf16x8*)(As + (wy * (MT / 2) + mt * 16 + (l & 15)) * 32 + (l >> 4) * 8);
#pragma unroll
    for (int nt = 0; nt < NTI; nt++)
      bfr[nt] = *(const bf16x8*)(Bs + (wx * (NT / 2) + nt * 16 + (l & 15)) * 32 + (l >> 4) * 8);
#pragma unroll
    for (int mt = 0; mt < MTI; mt++)
#pragma unroll
      for (int nt = 0; nt < NTI; nt++)
        acc[mt][nt] = __builtin_amdgcn_mfma_f32_16x16x32_bf16(af[mt], bfr[nt], acc[mt][nt], 0, 0, 0);
    __syncthreads();
  }
  // epilogue: D row = (l>>4)*4 + r, col = l&15
  const size_t cbase = (size_t)bz * sC;
#pragma unroll
  for (int mt = 0; mt < MTI; mt++) {
#pragma unroll
    for (int r = 0; r < 4; r++) {
      const int m = m0 + wy * (MT / 2) + mt * 16 + (l >> 4) * 4 + r;
      float bv = (BIAS_MODE == 1) ? bias[m] : 0.f;
#pragma unroll
      for (int nt = 0; nt < NTI; nt++) {
        const int n = n0 + wx * (NT / 2) + nt * 16 + (l & 15);
        float v = acc[mt][nt][r] * scale + bv;
        if (BIAS_MODE == 2) v += bias[n];
        if (HAS_RES) v += res[cbase + (size_t)m * N + n];
        if (OUT_F32) ((float*)Cout)[cbase + (size_t)m * N + n] = v;
        else ((__hip_bfloat16*)Cout)[cbase + (size_t)m * N + n] = __float2bfloat16(v);
      }
    }
  }
  if constexpr (STATS) {
    static_assert(!STATS || (MT == 128 && NT == 128), "stats needs 128x128");
    // per-column (n) max and sum-of-exp over this block's 128 m-values
    float* sred1 = (float*)As;          // [w][nt][16] = 256 floats
    float* sred2 = (float*)As + 512;    // disjoint region
    float cm[NTI], bs[NTI];
#pragma unroll
    for (int nt = 0; nt < NTI; nt++) {
      float m = -1e30f;
#pragma unroll
      for (int mt = 0; mt < MTI; mt++)
#pragma unroll
        for (int r = 0; r < 4; r++) m = fmaxf(m, acc[mt][nt][r] * scale);
      m = fmaxf(m, __shfl_xor(m, 16));
      m = fmaxf(m, __shfl_xor(m, 32));
      if (l < 16) sred1[(w * NTI + nt) * 16 + l] = m;
    }
    __syncthreads();
#pragma unroll
    for (int nt = 0; nt < NTI; nt++) {
      // combine the two wy halves sharing this wx
      float bm = fmaxf(sred1[(wx * NTI + nt) * 16 + (l & 15)],
                       sred1[((2 + wx) * NTI + nt) * 16 + (l & 15)]);
      cm[nt] = bm;
      float s = 0.f;
#pragma unroll
      for (int mt = 0; mt < MTI; mt++)
#pragma unroll
        for (int r = 0; r < 4; r++) s += __expf(acc[mt][nt][r] * scale - bm);
      s += __shfl_xor(s, 16);
      s += __shfl_xor(s, 32);
      if (l < 16) sred2[(w * NTI + nt) * 16 + l] = s;
    }
    __syncthreads();
    if (wy == 0 && l < 16) {
#pragma unroll
      for (int nt = 0; nt < NTI; nt++) {
        float stot = sred2[(wx * NTI + nt) * 16 + l] + sred2[((2 + wx) * NTI + nt) * 16 + l];
        int i = n0 + wx * 64 + nt * 16 + l;
        size_t idx = ((size_t)bz * gridDim.y + blockIdx.y) * N + i;
        pmax_g[idx] = cm[nt];
        psum_g[idx] = stot;
      }
    }
  }
}

// ---------------- softmax combine + apply (column softmax over St[j][i]) ----------------
__global__ __launch_bounds__(256) void softmax_comb(const float* __restrict__ pmax,
                                                    const float* __restrict__ psum,
                                                    float* __restrict__ cmax, float* __restrict__ cinv) {
  int idx = blockIdx.x * 256 + threadIdx.x;  // b*NDIM + i
  int b = idx >> 12, i = idx & (NDIM - 1);
  float M = -1e30f;
  for (int bc = 0; bc < 32; bc++) M = fmaxf(M, pmax[((size_t)b * 32 + bc) * NDIM + i]);
  float s = 0.f;
  for (int bc = 0; bc < 32; bc++) {
    size_t o = ((size_t)b * 32 + bc) * NDIM + i;
    s += psum[o] * __expf(pmax[o] - M);
  }
  cmax[idx] = M;
  cinv[idx] = 1.0f / s;
}

__global__ __launch_bounds__(256) void softmax_apply(__hip_bfloat16* __restrict__ St,
                                                     const float* __restrict__ cmax,
                                                     const float* __restrict__ cinv) {
  int b = blockIdx.z;
  int i = blockIdx.x * 256 + threadIdx.x;
  int j0 = blockIdx.y * 512;
  float M = cmax[b * NDIM + i], inv = cinv[b * NDIM + i];
  __hip_bfloat16* p = St + (size_t)b * NDIM * NDIM + (size_t)j0 * NDIM + i;
  for (int j = 0; j < 512; j++) {
    float v = __bfloat162float(p[(size_t)j * NDIM]);
    p[(size_t)j * NDIM] = __float2bfloat16(__expf(v - M) * inv);
  }
}

extern "C" void kernel_launch(void* const* d_in, const int* in_sizes, int n_in,
                              void* d_out, int out_size, void* d_ws, size_t ws_size,
                              hipStream_t stream) {
  const float* x      = (const float*)d_in[0];
  const float* norm_w = (const float*)d_in[1];
  const float* norm_b = (const float*)d_in[2];
  const float* wq = (const float*)d_in[3];
  const float* bq = (const float*)d_in[4];
  const float* wk = (const float*)d_in[5];
  const float* bk = (const float*)d_in[6];
  const float* wv = (const float*)d_in[7];
  const float* bv = (const float*)d_in[8];
  const float* wp = (const float*)d_in[9];
  const float* bp = (const float*)d_in[10];
  float* out = (float*)d_out;

  const long CN = (long)CDIM * NDIM;
  const long NN = (long)NDIM * NDIM;
  char* p = (char*)d_ws;
  auto carve = [&](size_t bytes) { char* r = p; p += (bytes + 255) & ~(size_t)255; return r; };
  __hip_bfloat16* h_t  = (__hip_bfloat16*)carve(BATCH * CN * 2);  // [B,N,C]
  __hip_bfloat16* wb   = (__hip_bfloat16*)carve(4 * 512 * 512 * 2);
  __hip_bfloat16* q_t  = (__hip_bfloat16*)carve(BATCH * CN * 2);  // [B,N,C]
  __hip_bfloat16* k_t  = (__hip_bfloat16*)carve(BATCH * CN * 2);  // [B,N,C]
  __hip_bfloat16* vb   = (__hip_bfloat16*)carve(BATCH * CN * 2);  // [B,C,N]
  __hip_bfloat16* ht2  = (__hip_bfloat16*)carve(BATCH * CN * 2);  // [B,N,C]
  __hip_bfloat16* St   = (__hip_bfloat16*)carve(BATCH * NN * 2);  // [B,N,N] S^T -> P^T
  float2* stats = (float2*)carve(BATCH * NGROUPS * sizeof(float2));
  float2* gnpart = (float2*)carve(1024 * sizeof(float2));
  float* pmax = (float*)carve((size_t)BATCH * 32 * NDIM * 4);
  float* psum = (float*)carve((size_t)BATCH * 32 * NDIM * 4);
  float* cmax = (float*)carve(BATCH * NDIM * 4);
  float* cinv = (float*)carve(BATCH * NDIM * 4);
  __hip_bfloat16* wbq = wb;
  __hip_bfloat16* wbk = wb + 262144;
  __hip_bfloat16* wbv = wb + 524288;
  __hip_bfloat16* wbp = wb + 786432;

  const float scale = 0.044194173824159216f;  // 512^-0.5

  gn_stats_p1<<<dim3(1024), 256, 0, stream>>>(x, gnpart);
  gn_stats_p2<<<dim3(1), 64, 0, stream>>>(gnpart, stats);
  gn_apply_t<<<dim3(NDIM / 64, CDIM / 64, BATCH), 256, 0, stream>>>(x, stats, norm_w, norm_b, h_t);
  cvt_w<<<dim3(1024), 256, 0, stream>>>(wq, wk, wv, wp, wb);

  // q_t = h_t @ wq^T + bq -> [N, C]
  mfma_gemm_nt<128, 64, 2, false, false, false><<<dim3(CDIM / 64, NDIM / 128, BATCH), 256, 0, stream>>>(
      h_t, wbq, bq, nullptr, q_t, nullptr, nullptr, NDIM, CDIM, CDIM, CN, 0, CN, 1.0f);
  // k_t = h_t @ wk^T + bk -> [N, C]
  mfma_gemm_nt<128, 64, 2, false, false, false><<<dim3(CDIM / 64, NDIM / 128, BATCH), 256, 0, stream>>>(
      h_t, wbk, bk, nullptr, k_t, nullptr, nullptr, NDIM, CDIM, CDIM, CN, 0, CN, 1.0f);
  // v = wv @ h_t^T + bv -> [C, N]
  mfma_gemm_nt<64, 128, 1, false, false, false><<<dim3(NDIM / 128, CDIM / 64, BATCH), 256, 0, stream>>>(
      wbv, h_t, bv, nullptr, vb, nullptr, nullptr, CDIM, NDIM, CDIM, 0, CN, CN, 1.0f);
  // St = k_t @ q_t^T * scale -> [N, N], with fused column stats
  mfma_gemm_nt<128, 128, 0, false, false, true><<<dim3(NDIM / 128, NDIM / 128, BATCH), 256, 0, stream>>>(
      k_t, q_t, nullptr, nullptr, St, pmax, psum, NDIM, NDIM, CDIM, CN, CN, NN, scale);
  softmax_comb<<<dim3(32), 256, 0, stream>>>(pmax, psum, cmax, cinv);
  softmax_apply<<<dim3(16, 8, BATCH), 256, 0, stream>>>(St, cmax, cinv);
  // ht2 = Pt @ v^T -> [N, C]
  mfma_gemm_nt<128, 64, 0, false, false, false><<<dim3(CDIM / 64, NDIM / 128, BATCH), 256, 0, stream>>>(
      St, vb, nullptr, nullptr, ht2, nullptr, nullptr, NDIM, CDIM, NDIM, NN, CN, CN, 1.0f);
  // out = wp @ ht2^T + bp + x -> [C, N] fp32
  mfma_gemm_nt<64, 128, 1, true, true, false><<<dim3(NDIM / 128, CDIM / 64, BATCH), 256, 0, stream>>>(
      wbp, ht2, bp, x, out, nullptr, nullptr, CDIM, NDIM, CDIM, 0, CN, CN, 1.0f);
}

// Round 5
// 301.896 us; speedup vs baseline: 5.7805x; 1.1217x over previous
//
#include <hip/hip_runtime.h>
#include <hip/hip_bf16.h>

// B=2, C=512, H=W=64 -> N=4096, 32 groups of 16 channels
#define BATCH 2
#define CDIM 512
#define NDIM 4096
#define NGROUPS 32
#define CHPG 16
#define GN_EPS 1e-6f

typedef __attribute__((ext_vector_type(8))) short bf16x8;   // 8 bf16 = 4 VGPRs
typedef __attribute__((ext_vector_type(4))) float f32x4;

__device__ __forceinline__ void gl_lds16(const void* g, void* lds) {
  __builtin_amdgcn_global_load_lds((__attribute__((address_space(1))) void*)(g),
                                   (__attribute__((address_space(3))) void*)(lds), 16, 0, 0);
}

__device__ __forceinline__ short bf16_bits(float v) {
  __hip_bfloat16 h = __float2bfloat16(v);
  union { __hip_bfloat16 h; short s; } u;
  u.h = h;
  return u.s;
}

// ---------------- GroupNorm stats, two-stage ----------------
__global__ __launch_bounds__(256) void gn_stats_p1(const float* __restrict__ x,
                                                   float2* __restrict__ part) {
  int blk = blockIdx.x;
  int chunk = blk & 15, bg = blk >> 4;
  const float4* p = (const float4*)(x + (size_t)bg * (CHPG * NDIM) + chunk * 4096);
  float s = 0.f, ss = 0.f;
#pragma unroll
  for (int t = 0; t < 4; t++) {
    float4 v = p[threadIdx.x + t * 256];
    s += v.x + v.y + v.z + v.w;
    ss += v.x * v.x + v.y * v.y + v.z * v.z + v.w * v.w;
  }
  int w = threadIdx.x >> 6, l = threadIdx.x & 63;
#pragma unroll
  for (int off = 32; off > 0; off >>= 1) {
    s += __shfl_down(s, off);
    ss += __shfl_down(ss, off);
  }
  __shared__ float r1[4], r2[4];
  if (l == 0) { r1[w] = s; r2[w] = ss; }
  __syncthreads();
  if (threadIdx.x == 0)
    part[blk] = make_float2(r1[0] + r1[1] + r1[2] + r1[3], r2[0] + r2[1] + r2[2] + r2[3]);
}

__global__ __launch_bounds__(64) void gn_stats_p2(const float2* __restrict__ part,
                                                  float2* __restrict__ stats) {
  int bg = threadIdx.x;  // 64
  float s = 0.f, ss = 0.f;
#pragma unroll
  for (int c = 0; c < 16; c++) {
    float2 v = part[bg * 16 + c];
    s += v.x; ss += v.y;
  }
  const float inv = 1.0f / (CHPG * NDIM);
  float mean = s * inv;
  float var = ss * inv - mean * mean;
  stats[bg] = make_float2(mean, rsqrtf(var + GN_EPS));
}

// ------ GroupNorm apply + transpose to channel-last bf16: h_t[b][n][c] ------
__global__ __launch_bounds__(256) void gn_apply_t(const float* __restrict__ x,
                                                  const float2* __restrict__ stats,
                                                  const float* __restrict__ w,
                                                  const float* __restrict__ bias,
                                                  __hip_bfloat16* __restrict__ ht) {
  __shared__ __hip_bfloat16 tile[64][66];
  int b = blockIdx.z, c0 = blockIdx.y * 64, n0 = blockIdx.x * 64;
  int tq = threadIdx.x >> 6;
  int tl = threadIdx.x & 63;
#pragma unroll
  for (int i = 0; i < 16; i++) {
    int cl = tq * 16 + i;
    int c = c0 + cl;
    float2 st = stats[b * NGROUPS + (c >> 4)];
    float v = x[((size_t)b * CDIM + c) * NDIM + n0 + tl];
    v = (v - st.x) * st.y * w[c] + bias[c];
    tile[tl][cl] = __float2bfloat16(v);
  }
  __syncthreads();
#pragma unroll
  for (int i = 0; i < 16; i++) {
    int nl = tq * 16 + i;
    ht[((size_t)b * NDIM + n0 + nl) * CDIM + c0 + tl] = tile[nl][tl];
  }
}

// ------------- fp32 -> bf16 for the four 512x512 weights -------------
__global__ __launch_bounds__(256) void cvt_w(const float* __restrict__ a, const float* __restrict__ b,
                                             const float* __restrict__ c, const float* __restrict__ d,
                                             __hip_bfloat16* __restrict__ o) {
  int i = blockIdx.x * 256 + threadIdx.x;
  o[i]          = __float2bfloat16(a[i]);
  o[i + 262144] = __float2bfloat16(b[i]);
  o[i + 524288] = __float2bfloat16(c[i]);
  o[i + 786432] = __float2bfloat16(d[i]);
}

// ---------------- MFMA NT GEMM, MT x NT tile ----------------
// C[m][n] = scale * sum_k A[m][k]*B[n][k]  (+bias) (+res)
// A: [M,K] bf16, B: [N,K] bf16, both row-major. BK=32, 4 waves (2x2).
// BIAS_MODE: 0 none, 1 bias[m], 2 bias[n]. STATS (needs 128x128): write
// per-block column max & sum-of-exp to pmax/psum.
// SWIZ (needs gridDim (8,32,z)): remap so the 8 blocks sharing an A row-tile
// land on ONE XCD (round-robin %8 of linear dispatch id) -> A fetched once/L2.
template <int MT, int NT, int BIAS_MODE, bool HAS_RES, bool OUT_F32, bool STATS, bool SWIZ, int MINB>
__global__ __launch_bounds__(256, MINB) void mfma_gemm_nt(
    const __hip_bfloat16* __restrict__ A, const __hip_bfloat16* __restrict__ B,
    const float* __restrict__ bias, const float* __restrict__ res,
    void* __restrict__ Cout, float* __restrict__ pmax_g, float* __restrict__ psum_g,
    int M, int N, int K, long sA, long sB, long sC, float scale) {
  constexpr int MTI = MT / 32, NTI = NT / 32;   // 16x16 acc tiles per wave
  __shared__ __hip_bfloat16 As[MT * 32];
  __shared__ __hip_bfloat16 Bs[NT * 32];
  const int tid = threadIdx.x;
  const int w = tid >> 6, l = tid & 63;
  const int wy = w >> 1, wx = w & 1;
  const int bz = blockIdx.z;
  int bx = blockIdx.x, by = blockIdx.y;
  if constexpr (SWIZ) {
    // valid for grid (8, 32): l2 = by*8+bx; partners (all bx, same by') share XCD
    int l2 = by * 8 + bx;
    int xcd = l2 & 7, s = l2 >> 3;  // s in [0,32)
    by = xcd + (s & 3) * 8;
    bx = s >> 2;
  }
  const int m0 = by * MT, n0 = bx * NT;
  f32x4 acc[MTI][NTI] = {};
  // staging: one gl_lds16 issue = 64 lanes x 16B = 16 rows x 64B
  const int arow = w * (MT / 4) + (l >> 2);
  const int brow = w * (NT / 4) + (l >> 2);
  const char* Ag = (const char*)(A + (size_t)bz * sA + (size_t)(m0 + arow) * K) + (l & 3) * 16;
  const char* Bg = (const char*)(B + (size_t)bz * sB + (size_t)(n0 + brow) * K) + (l & 3) * 16;
  char* Al = (char*)As + w * (MT * 16);
  char* Bl = (char*)Bs + w * (NT * 16);
  const size_t radv = (size_t)K * 32;  // +16 rows (bf16)
  for (int k0 = 0; k0 < K; k0 += 32) {
    gl_lds16(Ag, Al);
    if (MT == 128) gl_lds16(Ag + radv, Al + 1024);
    gl_lds16(Bg, Bl);
    if (NT == 128) gl_lds16(Bg + radv, Bl + 1024);
    Ag += 64; Bg += 64;
    __syncthreads();
    bf16x8 af[MTI], bfr[NTI];
#pragma unroll
    for (int mt = 0; mt < MTI; mt++)
      af[mt] = *(const bf16x8*)(As + (wy * (MT / 2) + mt * 16 + (l & 15)) * 32 + (l >> 4) * 8);
#pragma unroll
    for (int nt = 0; nt < NTI; nt++)
      bfr[nt] = *(const bf16x8*)(Bs + (wx * (NT / 2) + nt * 16 + (l & 15)) * 32 + (l >> 4) * 8);
#pragma unroll
    for (int mt = 0; mt < MTI; mt++)
#pragma unroll
      for (int nt = 0; nt < NTI; nt++)
        acc[mt][nt] = __builtin_amdgcn_mfma_f32_16x16x32_bf16(af[mt], bfr[nt], acc[mt][nt], 0, 0, 0);
    __syncthreads();
  }
  // epilogue: D row = (l>>4)*4 + r, col = l&15
  const size_t cbase = (size_t)bz * sC;
#pragma unroll
  for (int mt = 0; mt < MTI; mt++) {
#pragma unroll
    for (int r = 0; r < 4; r++) {
      const int m = m0 + wy * (MT / 2) + mt * 16 + (l >> 4) * 4 + r;
      float bv = (BIAS_MODE == 1) ? bias[m] : 0.f;
#pragma unroll
      for (int nt = 0; nt < NTI; nt++) {
        const int n = n0 + wx * (NT / 2) + nt * 16 + (l & 15);
        float v = acc[mt][nt][r] * scale + bv;
        if (BIAS_MODE == 2) v += bias[n];
        if (HAS_RES) v += res[cbase + (size_t)m * N + n];
        if (OUT_F32) ((float*)Cout)[cbase + (size_t)m * N + n] = v;
        else ((__hip_bfloat16*)Cout)[cbase + (size_t)m * N + n] = __float2bfloat16(v);
      }
    }
  }
  if constexpr (STATS) {
    // per-column (n) max and sum-of-exp over this block's 128 m-values
    float* sred1 = (float*)As;          // [w][nt][16]
    float* sred2 = (float*)As + 512;
    float cm[NTI];
#pragma unroll
    for (int nt = 0; nt < NTI; nt++) {
      float m = -1e30f;
#pragma unroll
      for (int mt = 0; mt < MTI; mt++)
#pragma unroll
        for (int r = 0; r < 4; r++) m = fmaxf(m, acc[mt][nt][r] * scale);
      m = fmaxf(m, __shfl_xor(m, 16));
      m = fmaxf(m, __shfl_xor(m, 32));
      if (l < 16) sred1[(w * NTI + nt) * 16 + l] = m;
    }
    __syncthreads();
#pragma unroll
    for (int nt = 0; nt < NTI; nt++) {
      float bm = fmaxf(sred1[(wx * NTI + nt) * 16 + (l & 15)],
                       sred1[((2 + wx) * NTI + nt) * 16 + (l & 15)]);
      cm[nt] = bm;
      float s = 0.f;
#pragma unroll
      for (int mt = 0; mt < MTI; mt++)
#pragma unroll
        for (int r = 0; r < 4; r++) s += __expf(acc[mt][nt][r] * scale - bm);
      s += __shfl_xor(s, 16);
      s += __shfl_xor(s, 32);
      if (l < 16) sred2[(w * NTI + nt) * 16 + l] = s;
    }
    __syncthreads();
    if (wy == 0 && l < 16) {
#pragma unroll
      for (int nt = 0; nt < NTI; nt++) {
        float stot = sred2[(wx * NTI + nt) * 16 + l] + sred2[((2 + wx) * NTI + nt) * 16 + l];
        int i = n0 + wx * 64 + nt * 16 + l;
        size_t idx = ((size_t)bz * gridDim.y + blockIdx.y) * N + i;  // raw blockIdx (no SWIZ w/ STATS)
        pmax_g[idx] = cm[nt];
        psum_g[idx] = stot;
      }
    }
  }
}

// ---------------- softmax combine + apply (softmax over j = St's row dim) ----------------
__global__ __launch_bounds__(256) void softmax_comb(const float* __restrict__ pmax,
                                                    const float* __restrict__ psum,
                                                    float* __restrict__ cmax, float* __restrict__ cinv) {
  int idx = blockIdx.x * 256 + threadIdx.x;  // b*NDIM + i
  int b = idx >> 12, i = idx & (NDIM - 1);
  float M = -1e30f;
  for (int bc = 0; bc < 32; bc++) M = fmaxf(M, pmax[((size_t)b * 32 + bc) * NDIM + i]);
  float s = 0.f;
  for (int bc = 0; bc < 32; bc++) {
    size_t o = ((size_t)b * 32 + bc) * NDIM + i;
    s += psum[o] * __expf(pmax[o] - M);
  }
  cmax[idx] = M;
  cinv[idx] = 1.0f / s;
}

// one block per (j-row, b); 256 threads x 16 bf16 = 4096 i's, 16B vector loads
__global__ __launch_bounds__(256) void softmax_apply(__hip_bfloat16* __restrict__ St,
                                                     const float* __restrict__ cmax,
                                                     const float* __restrict__ cinv) {
  int b = blockIdx.y;
  size_t row = blockIdx.x;
  int i0 = threadIdx.x * 16;
  __hip_bfloat16* p = St + ((size_t)b * NDIM + row) * NDIM + i0;
  const float4* pm = (const float4*)(cmax + (size_t)b * NDIM + i0);
  const float4* pz = (const float4*)(cinv + (size_t)b * NDIM + i0);
  bf16x8 d0 = *(const bf16x8*)p;
  bf16x8 d1 = *(const bf16x8*)(p + 8);
  float4 M4[4], Z4[4];
#pragma unroll
  for (int t = 0; t < 4; t++) { M4[t] = pm[t]; Z4[t] = pz[t]; }
  const float* Mf = (const float*)M4;
  const float* Zf = (const float*)Z4;
  bf16x8 o0, o1;
#pragma unroll
  for (int e = 0; e < 8; e++) {
    union { short s; __hip_bfloat16 h; } u; u.s = d0[e];
    o0[e] = bf16_bits(__expf(__bfloat162float(u.h) - Mf[e]) * Zf[e]);
  }
#pragma unroll
  for (int e = 0; e < 8; e++) {
    union { short s; __hip_bfloat16 h; } u; u.s = d1[e];
    o1[e] = bf16_bits(__expf(__bfloat162float(u.h) - Mf[8 + e]) * Zf[8 + e]);
  }
  *(bf16x8*)p = o0;
  *(bf16x8*)(p + 8) = o1;
}

extern "C" void kernel_launch(void* const* d_in, const int* in_sizes, int n_in,
                              void* d_out, int out_size, void* d_ws, size_t ws_size,
                              hipStream_t stream) {
  const float* x      = (const float*)d_in[0];
  const float* norm_w = (const float*)d_in[1];
  const float* norm_b = (const float*)d_in[2];
  const float* wq = (const float*)d_in[3];
  const float* bq = (const float*)d_in[4];
  const float* wk = (const float*)d_in[5];
  const float* bk = (const float*)d_in[6];
  const float* wv = (const float*)d_in[7];
  const float* bv = (const float*)d_in[8];
  const float* wp = (const float*)d_in[9];
  const float* bp = (const float*)d_in[10];
  float* out = (float*)d_out;

  const long CN = (long)CDIM * NDIM;
  const long NN = (long)NDIM * NDIM;
  char* p = (char*)d_ws;
  auto carve = [&](size_t bytes) { char* r = p; p += (bytes + 255) & ~(size_t)255; return r; };
  __hip_bfloat16* h_t  = (__hip_bfloat16*)carve(BATCH * CN * 2);  // [B,N,C]
  __hip_bfloat16* wb   = (__hip_bfloat16*)carve(4 * 512 * 512 * 2);
  __hip_bfloat16* q_t  = (__hip_bfloat16*)carve(BATCH * CN * 2);  // [B,N,C]
  __hip_bfloat16* k_t  = (__hip_bfloat16*)carve(BATCH * CN * 2);  // [B,N,C]
  __hip_bfloat16* vb   = (__hip_bfloat16*)carve(BATCH * CN * 2);  // [B,C,N]
  __hip_bfloat16* ht2  = (__hip_bfloat16*)carve(BATCH * CN * 2);  // [B,N,C]
  __hip_bfloat16* St   = (__hip_bfloat16*)carve(BATCH * NN * 2);  // [B,N,N] S^T -> P^T
  float2* stats = (float2*)carve(BATCH * NGROUPS * sizeof(float2));
  float2* gnpart = (float2*)carve(1024 * sizeof(float2));
  float* pmax = (float*)carve((size_t)BATCH * 32 * NDIM * 4);
  float* psum = (float*)carve((size_t)BATCH * 32 * NDIM * 4);
  float* cmax = (float*)carve(BATCH * NDIM * 4);
  float* cinv = (float*)carve(BATCH * NDIM * 4);
  __hip_bfloat16* wbq = wb;
  __hip_bfloat16* wbk = wb + 262144;
  __hip_bfloat16* wbv = wb + 524288;
  __hip_bfloat16* wbp = wb + 786432;

  const float scale = 0.044194173824159216f;  // 512^-0.5

  gn_stats_p1<<<dim3(1024), 256, 0, stream>>>(x, gnpart);
  gn_stats_p2<<<dim3(1), 64, 0, stream>>>(gnpart, stats);
  gn_apply_t<<<dim3(NDIM / 64, CDIM / 64, BATCH), 256, 0, stream>>>(x, stats, norm_w, norm_b, h_t);
  cvt_w<<<dim3(1024), 256, 0, stream>>>(wq, wk, wv, wp, wb);

  // q_t = h_t @ wq^T + bq -> [N, C]   (SWIZ: A=h_t shared by 8 x-partners)
  mfma_gemm_nt<128, 64, 2, false, false, false, true, 2><<<dim3(8, 32, BATCH), 256, 0, stream>>>(
      h_t, wbq, bq, nullptr, q_t, nullptr, nullptr, NDIM, CDIM, CDIM, CN, 0, CN, 1.0f);
  // k_t = h_t @ wk^T + bk -> [N, C]
  mfma_gemm_nt<128, 64, 2, false, false, false, true, 2><<<dim3(8, 32, BATCH), 256, 0, stream>>>(
      h_t, wbk, bk, nullptr, k_t, nullptr, nullptr, NDIM, CDIM, CDIM, CN, 0, CN, 1.0f);
  // v = wv @ h_t^T + bv -> [C, N]   (grid (32,8): B-partners already same-XCD)
  mfma_gemm_nt<64, 128, 1, false, false, false, false, 2><<<dim3(32, 8, BATCH), 256, 0, stream>>>(
      wbv, h_t, bv, nullptr, vb, nullptr, nullptr, CDIM, NDIM, CDIM, 0, CN, CN, 1.0f);
  // St = k_t @ q_t^T * scale -> [N, N], fused column stats; 3 blocks/CU
  mfma_gemm_nt<128, 128, 0, false, false, true, false, 3><<<dim3(32, 32, BATCH), 256, 0, stream>>>(
      k_t, q_t, nullptr, nullptr, St, pmax, psum, NDIM, NDIM, CDIM, CN, CN, NN, scale);
  softmax_comb<<<dim3(32), 256, 0, stream>>>(pmax, psum, cmax, cinv);
  softmax_apply<<<dim3(NDIM, BATCH), 256, 0, stream>>>(St, cmax, cinv);
  // ht2 = Pt @ v^T -> [N, C]   (SWIZ: A=St is the 64MB operand)
  mfma_gemm_nt<128, 64, 0, false, false, false, true, 2><<<dim3(8, 32, BATCH), 256, 0, stream>>>(
      St, vb, nullptr, nullptr, ht2, nullptr, nullptr, NDIM, CDIM, NDIM, NN, CN, CN, 1.0f);
  // out = wp @ ht2^T + bp + x -> [C, N] fp32
  mfma_gemm_nt<64, 128, 1, true, true, false, false, 2><<<dim3(32, 8, BATCH), 256, 0, stream>>>(
      wbp, ht2, bp, x, out, nullptr, nullptr, CDIM, NDIM, CDIM, 0, CN, CN, 1.0f);
}